// Round 1
// baseline (41.438 us; speedup 1.0000x reference)
//
#include <hip/hip_runtime.h>

// SurvRankingLoss: loss = -mean over comparable pairs of sigmoid(z_i - z_j)
// comparable(i,j) = (t_i < t_j) && (event_i > 0), event = 1 - censorship.
// B = 8192. Pure compute-bound O(B^2); inputs fit in L2.

constexpr int THREADS = 256;
constexpr int JT = 256;   // j-tile per block

__global__ __launch_bounds__(256) void surv_pairs(
    const float* __restrict__ z, const float* __restrict__ ct,
    unsigned long long* __restrict__ sum_q, unsigned int* __restrict__ cnt_q,
    int B)
{
    __shared__ float s_t[JT];
    __shared__ float s_e[JT];

    const int tid = threadIdx.x;
    const int njc = B / JT;
    const int ib  = blockIdx.x / njc;   // i-block
    const int jc  = blockIdx.x % njc;   // j-chunk
    const int j0  = jc * JT;

    // stage j-tile: times and exp(z_j)
    {
        const int j = j0 + tid;
        s_t[tid] = ct[2 * j + 1];
        s_e[tid] = __expf(z[j]);
    }

    // per-thread i row
    const int i = ib * THREADS + tid;
    const float censi = ct[2 * i];
    const float ti    = ct[2 * i + 1];
    // event_i <= 0  ->  gate with +INF so (tgate < t_j) is always false
    const float tgate = ((1.0f - censi) > 0.0f) ? ti : __builtin_inff();
    const float ei    = __expf(z[i]);

    __syncthreads();

    float fsum = 0.0f;
    int   cnt  = 0;
    const float4* t4 = reinterpret_cast<const float4*>(s_t);
    const float4* e4 = reinterpret_cast<const float4*>(s_e);

#pragma unroll 4
    for (int q = 0; q < JT / 4; ++q) {
        const float4 t = t4[q];
        const float4 e = e4[q];
        // sigmoid(z_i - z_j) = e_i / (e_i + e_j); rcp is single v_rcp_f32
        { bool c = tgate < t.x; float sg = ei * __builtin_amdgcn_rcpf(ei + e.x); fsum += c ? sg : 0.0f; cnt += c; }
        { bool c = tgate < t.y; float sg = ei * __builtin_amdgcn_rcpf(ei + e.y); fsum += c ? sg : 0.0f; cnt += c; }
        { bool c = tgate < t.z; float sg = ei * __builtin_amdgcn_rcpf(ei + e.z); fsum += c ? sg : 0.0f; cnt += c; }
        { bool c = tgate < t.w; float sg = ei * __builtin_amdgcn_rcpf(ei + e.w); fsum += c ? sg : 0.0f; cnt += c; }
    }

    // wave (64-lane) reduction
    for (int off = 32; off > 0; off >>= 1) {
        fsum += __shfl_down(fsum, off);
        cnt  += __shfl_down(cnt, off);
    }

    __shared__ float wsum[4];
    __shared__ int   wcnt[4];
    const int wid  = tid >> 6;
    const int lane = tid & 63;
    if (lane == 0) { wsum[wid] = fsum; wcnt[wid] = cnt; }
    __syncthreads();

    if (tid == 0) {
        const float bs = wsum[0] + wsum[1] + wsum[2] + wsum[3];
        const int   bc = wcnt[0] + wcnt[1] + wcnt[2] + wcnt[3];
        // fixed-point 2^26 — integer atomics are associative => deterministic
        const unsigned long long q =
            (unsigned long long)((double)bs * 67108864.0 + 0.5);
        atomicAdd(sum_q, q);
        atomicAdd(cnt_q, (unsigned int)bc);
    }
}

__global__ void surv_finalize(const unsigned long long* __restrict__ sum_q,
                              const unsigned int* __restrict__ cnt_q,
                              float* __restrict__ out)
{
    const unsigned long long q = *sum_q;
    const unsigned int n = *cnt_q;
    const double total = (double)q * (1.0 / 67108864.0);
    out[0] = (n > 0) ? (float)(-(total / (double)n)) : 0.0f;
}

extern "C" void kernel_launch(void* const* d_in, const int* in_sizes, int n_in,
                              void* d_out, int out_size, void* d_ws, size_t ws_size,
                              hipStream_t stream)
{
    const float* z  = (const float*)d_in[0];   // (B,1) f32
    const float* ct = (const float*)d_in[1];   // (B,2) f32 [censorship, time]
    float* out = (float*)d_out;
    const int B = in_sizes[0];

    unsigned long long* sum_q = (unsigned long long*)d_ws;
    unsigned int*       cnt_q = (unsigned int*)((char*)d_ws + 8);

    hipMemsetAsync(d_ws, 0, 16, stream);

    const int blocks = (B / THREADS) * (B / JT);   // 32 * 32 = 1024
    surv_pairs<<<blocks, THREADS, 0, stream>>>(z, ct, sum_q, cnt_q, B);
    surv_finalize<<<1, 1, 0, stream>>>(sum_q, cnt_q, out);
}

// Round 3
// 25.668 us; speedup vs baseline: 1.6144x; 1.6144x over previous
//
#include <hip/hip_runtime.h>

// SurvRankingLoss: loss = -mean over comparable pairs of sigmoid(z_i - z_j)
// comparable(i,j) = (t_i < t_j) && (event_i > 0), event = 1 - censorship.
// B = 8192. Compute-bound O(B^2); only event rows (~50%) contribute, so we
// compact them per i-block. 3 dispatches, no atomics, no memset:
//   prep:  exp(z), deinterleave t, block-local event compaction (deterministic)
//   pairs: (i-block, j-chunk) tiles; per-block float partial -> fixed slot
//   fin:   fixed-order tree reduction of 1024 partials in double
// Determinism: partitioning is fixed, every ws cell read was written this call.

constexpr int THREADS = 256;
constexpr int JT = 256;   // j-tile per block

__global__ __launch_bounds__(256) void surv_prep(
    const float* __restrict__ z, const float* __restrict__ ct,
    float* __restrict__ E, float* __restrict__ T,
    float* __restrict__ TGC, float* __restrict__ EC, int* __restrict__ M)
{
    const int tid = threadIdx.x;
    const int i = blockIdx.x * THREADS + tid;

    const float zi   = z[i];
    const float e    = __expf(zi);
    const float cens = ct[2 * i];
    const float t    = ct[2 * i + 1];
    E[i] = e;
    T[i] = t;

    // block-local compaction of event rows (deterministic: fixed block->rows map)
    const bool ev = (1.0f - cens) > 0.0f;
    const unsigned long long mask = __ballot(ev);
    const int lane = tid & 63;
    const int wid  = tid >> 6;
    __shared__ int wcnt[4];
    if (lane == 0) wcnt[wid] = __popcll(mask);
    __syncthreads();
    int base = 0;
    for (int w = 0; w < wid; ++w) base += wcnt[w];
    const int pos = base + __popcll(mask & ((1ull << lane) - 1ull));
    const int o = blockIdx.x * THREADS;
    if (ev) { TGC[o + pos] = t; EC[o + pos] = e; }
    if (tid == 0) M[blockIdx.x] = wcnt[0] + wcnt[1] + wcnt[2] + wcnt[3];
}

__global__ __launch_bounds__(256) void surv_pairs(
    const float* __restrict__ E, const float* __restrict__ T,
    const float* __restrict__ TGC, const float* __restrict__ EC,
    const int* __restrict__ M, float2* __restrict__ P, int njc)
{
    __shared__ float s_t[JT];
    __shared__ float s_e[JT];

    const int tid = threadIdx.x;
    const int ib  = blockIdx.x / njc;   // i-block (compacted rows)
    const int jc  = blockIdx.x % njc;   // j-chunk
    const int j0  = jc * JT;

    s_t[tid] = T[j0 + tid];
    s_e[tid] = E[j0 + tid];

    const int m = M[ib];                 // uniform -> scalar load
    const bool act = tid < m;
    float tg = 0.0f, ei = 0.0f;
    if (act) {
        tg = TGC[ib * THREADS + tid];    // real time (event rows only)
        ei = EC[ib * THREADS + tid];
    }
    __syncthreads();

    float fsum = 0.0f;
    int   cnt  = 0;
    if (act) {   // whole waves with no active lanes skip the loop entirely
        const float4* t4 = reinterpret_cast<const float4*>(s_t);
        const float4* e4 = reinterpret_cast<const float4*>(s_e);
#pragma unroll 8
        for (int q = 0; q < JT / 4; ++q) {
            const float4 t = t4[q];
            const float4 e = e4[q];
            // sigmoid(z_i - z_j) = e_i / (e_i + e_j)
            { bool c = tg < t.x; float sg = ei * __builtin_amdgcn_rcpf(ei + e.x); fsum += c ? sg : 0.0f; cnt += c; }
            { bool c = tg < t.y; float sg = ei * __builtin_amdgcn_rcpf(ei + e.y); fsum += c ? sg : 0.0f; cnt += c; }
            { bool c = tg < t.z; float sg = ei * __builtin_amdgcn_rcpf(ei + e.z); fsum += c ? sg : 0.0f; cnt += c; }
            { bool c = tg < t.w; float sg = ei * __builtin_amdgcn_rcpf(ei + e.w); fsum += c ? sg : 0.0f; cnt += c; }
        }
    }

    // wave (64-lane) reduction
    for (int off = 32; off > 0; off >>= 1) {
        fsum += __shfl_down(fsum, off);
        cnt  += __shfl_down(cnt, off);
    }
    __shared__ float wsum[4];
    __shared__ int   wcnt[4];
    const int wid  = tid >> 6;
    const int lane = tid & 63;
    if (lane == 0) { wsum[wid] = fsum; wcnt[wid] = cnt; }
    __syncthreads();
    if (tid == 0) {
        const float bs = wsum[0] + wsum[1] + wsum[2] + wsum[3];
        const int   bc = wcnt[0] + wcnt[1] + wcnt[2] + wcnt[3];
        P[blockIdx.x] = make_float2(bs, (float)bc);   // every block writes its slot
    }
}

__global__ __launch_bounds__(256) void surv_fin(
    const float2* __restrict__ P, int nb, float* __restrict__ out)
{
    const int tid = threadIdx.x;
    double s = 0.0, c = 0.0;
    for (int k = tid; k < nb; k += THREADS) {   // fixed per-thread order
        const float2 p = P[k];
        s += p.x; c += p.y;
    }
    __shared__ double ss[THREADS];
    __shared__ double sc[THREADS];
    ss[tid] = s; sc[tid] = c;
    __syncthreads();
    for (int off = THREADS / 2; off > 0; off >>= 1) {   // fixed tree order
        if (tid < off) { ss[tid] += ss[tid + off]; sc[tid] += sc[tid + off]; }
        __syncthreads();
    }
    if (tid == 0) {
        const double n = sc[0];
        out[0] = (n > 0.0) ? (float)(-(ss[0] / n)) : 0.0f;
    }
}

extern "C" void kernel_launch(void* const* d_in, const int* in_sizes, int n_in,
                              void* d_out, int out_size, void* d_ws, size_t ws_size,
                              hipStream_t stream)
{
    const float* z  = (const float*)d_in[0];   // (B,1) f32
    const float* ct = (const float*)d_in[1];   // (B,2) f32 [censorship, time]
    float* out = (float*)d_out;
    const int B = in_sizes[0];

    const int NB  = B / THREADS;   // 32 i-blocks
    const int njc = B / JT;        // 32 j-chunks

    float* E   = (float*)d_ws;     // exp(z_j), j-indexed
    float* T   = E + B;            // t_j, j-indexed
    float* TGC = T + B;            // compacted t_i per i-block
    float* EC  = TGC + B;          // compacted exp(z_i) per i-block
    int*   M   = (int*)(EC + B);   // per-i-block event count
    float2* P  = (float2*)(M + ((NB + 1) & ~1));   // 8B-aligned partials

    surv_prep<<<NB, THREADS, 0, stream>>>(z, ct, E, T, TGC, EC, M);
    surv_pairs<<<NB * njc, THREADS, 0, stream>>>(E, T, TGC, EC, M, P, njc);
    surv_fin<<<1, THREADS, 0, stream>>>(P, NB * njc, out);
}

// Round 4
// 20.854 us; speedup vs baseline: 1.9871x; 1.2309x over previous
//
#include <hip/hip_runtime.h>

// SurvRankingLoss: loss = -mean over comparable pairs of sigmoid(z_i - z_j)
// comparable(i,j) = (t_i < t_j) && (event_i > 0), event = 1 - censorship.
// B = 8192. O(B^2) VALU-bound, but measured profile says per-dispatch graph
// overhead (~5-6 us) dominates -> fuse to 2 dispatches:
//   pairs: per (i-block, j-chunk) tile. Block stages its j-tile {t_j, exp(z_j)}
//          and compacts its own i-rows to event rows in LDS (block-local,
//          deterministic), then dense pair loop; partial -> fixed slot P[bid].
//   fin:   fixed-order tree reduction of 1024 partials in double.
// Determinism: fixed partitioning, fixed reduction order, every ws cell read
// was written this call. No atomics, no memsets.

constexpr int THREADS = 256;
constexpr int JT = 256;   // j-tile per block

__global__ __launch_bounds__(256) void surv_pairs(
    const float* __restrict__ z, const float* __restrict__ ct,
    float2* __restrict__ P, int njc)
{
    __shared__ float s_t[JT];        // t_j
    __shared__ float s_e[JT];        // exp(z_j)
    __shared__ float s_tg[THREADS];  // compacted t_i (event rows)
    __shared__ float s_ei[THREADS];  // compacted exp(z_i)
    __shared__ int   s_wcnt[4];

    const int tid = threadIdx.x;
    const int ib  = blockIdx.x / njc;   // i-block
    const int jc  = blockIdx.x % njc;   // j-chunk
    const int j0  = jc * JT;

    // stage j-tile
    {
        const int j = j0 + tid;
        s_t[tid] = ct[2 * j + 1];
        s_e[tid] = __expf(z[j]);
    }

    // load own i-row, block-local compaction of event rows (deterministic)
    const int i = ib * THREADS + tid;
    const float cens = ct[2 * i];
    const float ti   = ct[2 * i + 1];
    const float eii  = __expf(z[i]);
    const bool  ev   = (1.0f - cens) > 0.0f;
    const unsigned long long mask = __ballot(ev);
    const int lane = tid & 63;
    const int wid  = tid >> 6;
    if (lane == 0) s_wcnt[wid] = __popcll(mask);
    __syncthreads();
    int base = 0;
    for (int w = 0; w < wid; ++w) base += s_wcnt[w];
    const int m = s_wcnt[0] + s_wcnt[1] + s_wcnt[2] + s_wcnt[3];
    const int pos = base + __popcll(mask & ((1ull << lane) - 1ull));
    if (ev) { s_tg[pos] = ti; s_ei[pos] = eii; }
    __syncthreads();

    const bool act = tid < m;
    float tg = 0.0f, ei = 0.0f;
    if (act) { tg = s_tg[tid]; ei = s_ei[tid]; }

    float fsum = 0.0f;
    int   cnt  = 0;
    if (act) {   // waves past the compacted count skip the loop entirely
        const float4* t4 = reinterpret_cast<const float4*>(s_t);
        const float4* e4 = reinterpret_cast<const float4*>(s_e);
#pragma unroll 8
        for (int q = 0; q < JT / 4; ++q) {
            const float4 t = t4[q];
            const float4 e = e4[q];
            // sigmoid(z_i - z_j) = e_i / (e_i + e_j)
            { bool c = tg < t.x; float sg = ei * __builtin_amdgcn_rcpf(ei + e.x); fsum += c ? sg : 0.0f; cnt += c; }
            { bool c = tg < t.y; float sg = ei * __builtin_amdgcn_rcpf(ei + e.y); fsum += c ? sg : 0.0f; cnt += c; }
            { bool c = tg < t.z; float sg = ei * __builtin_amdgcn_rcpf(ei + e.z); fsum += c ? sg : 0.0f; cnt += c; }
            { bool c = tg < t.w; float sg = ei * __builtin_amdgcn_rcpf(ei + e.w); fsum += c ? sg : 0.0f; cnt += c; }
        }
    }

    // wave (64-lane) reduction
    for (int off = 32; off > 0; off >>= 1) {
        fsum += __shfl_down(fsum, off);
        cnt  += __shfl_down(cnt, off);
    }
    __shared__ float wsum[4];
    __shared__ int   wcnt2[4];
    if (lane == 0) { wsum[wid] = fsum; wcnt2[wid] = cnt; }
    __syncthreads();
    if (tid == 0) {
        const float bs = wsum[0] + wsum[1] + wsum[2] + wsum[3];
        const int   bc = wcnt2[0] + wcnt2[1] + wcnt2[2] + wcnt2[3];
        P[blockIdx.x] = make_float2(bs, (float)bc);   // every block writes its slot
    }
}

__global__ __launch_bounds__(256) void surv_fin(
    const float2* __restrict__ P, int nb, float* __restrict__ out)
{
    const int tid = threadIdx.x;
    double s = 0.0, c = 0.0;
    for (int k = tid; k < nb; k += THREADS) {   // fixed per-thread order
        const float2 p = P[k];
        s += p.x; c += p.y;
    }
    __shared__ double ss[THREADS];
    __shared__ double sc[THREADS];
    ss[tid] = s; sc[tid] = c;
    __syncthreads();
    for (int off = THREADS / 2; off > 0; off >>= 1) {   // fixed tree order
        if (tid < off) { ss[tid] += ss[tid + off]; sc[tid] += sc[tid + off]; }
        __syncthreads();
    }
    if (tid == 0) {
        const double n = sc[0];
        out[0] = (n > 0.0) ? (float)(-(ss[0] / n)) : 0.0f;
    }
}

extern "C" void kernel_launch(void* const* d_in, const int* in_sizes, int n_in,
                              void* d_out, int out_size, void* d_ws, size_t ws_size,
                              hipStream_t stream)
{
    const float* z  = (const float*)d_in[0];   // (B,1) f32
    const float* ct = (const float*)d_in[1];   // (B,2) f32 [censorship, time]
    float* out = (float*)d_out;
    const int B = in_sizes[0];

    const int NB  = B / THREADS;   // 32 i-blocks
    const int njc = B / JT;        // 32 j-chunks

    float2* P = (float2*)d_ws;     // per-block partials (sum, count)

    surv_pairs<<<NB * njc, THREADS, 0, stream>>>(z, ct, P, njc);
    surv_fin<<<1, THREADS, 0, stream>>>(P, NB * njc, out);
}